// Round 13
// baseline (600.694 us; speedup 1.0000x reference)
//
#include <hip/hip_runtime.h>
#include <math.h>

#define N_NODES 50000
#define E_EDGES 600000
#define DD 128
#define G_GRAPHS 512
#define K_CODES 512
#define Q_QUANT 3
#define FD_OUT 512
#define NEG_SLOPE 0.2f
#define LN_EPS 1e-5f

static __device__ __forceinline__ float lrelu(float v){ return v > 0.f ? v : NEG_SLOPE*v; }
static __device__ __forceinline__ float wsum16(float v){
#pragma unroll
  for (int m = 1; m < 16; m <<= 1) v += __shfl_xor(v, m);
  return v;
}
static __device__ __forceinline__ float wmax16(float v){
#pragma unroll
  for (int m = 1; m < 16; m <<= 1) v = fmaxf(v, __shfl_xor(v, m));
  return v;
}

#define EA_LD 130   // row pitch: 520B -> A-broadcast addrs land on distinct banks

// ---------------- fused transform: xl = x@W_l + b_l ; xr = x@W_r + b_r ----------------
// (unchanged — proven)
__global__ __launch_bounds__(256)
void k_xform2(const float* __restrict__ x,
              const float* __restrict__ W_l, const float* __restrict__ b_l,
              const float* __restrict__ W_r, const float* __restrict__ b_r,
              float* __restrict__ xl, float* __restrict__ xr, int n)
{
  __shared__ __align__(16) float xt[64*EA_LD];
  __shared__ __align__(16) float WtL[32*128];
  __shared__ __align__(16) float WtR[32*128];
  const int tid = threadIdx.x;
  const int r0 = blockIdx.x * 64;
  {
    const int q = tid & 63, eb = tid >> 6;
#pragma unroll
    for (int i = 0; i < 16; ++i){
      int e = eb + 4*i;
      int row = r0 + e;
      float2 v = make_float2(0.f, 0.f);
      if (row < n) v = *(const float2*)&x[row*DD + q*2];
      *(float2*)&xt[e*EA_LD + q*2] = v;
    }
  }
  const int eg = tid >> 4;
  const int cg = tid & 15;
  float accL[4][8], accR[4][8];
#pragma unroll
  for (int j = 0; j < 4; ++j)
#pragma unroll
    for (int u = 0; u < 8; ++u){ accL[j][u] = 0.f; accR[j][u] = 0.f; }

  for (int kq = 0; kq < 4; ++kq){
    __syncthreads();
    {
      const int c4 = tid & 31, kb = tid >> 5;
#pragma unroll
      for (int i = 0; i < 4; ++i){
        int kk = kb + 8*i;
        *(float4*)&WtL[kk*128 + c4*4] = *(const float4*)&W_l[(kq*32+kk)*DD + c4*4];
        *(float4*)&WtR[kk*128 + c4*4] = *(const float4*)&W_r[(kq*32+kk)*DD + c4*4];
      }
    }
    __syncthreads();
    const int kb2 = kq*32;
#pragma unroll 4
    for (int k = 0; k < 32; ++k){
      float aa[4];
#pragma unroll
      for (int j = 0; j < 4; ++j) aa[j] = xt[(eg*4+j)*EA_LD + kb2 + k];
      float bL[8], bR[8];
      *(float4*)&bL[0] = *(const float4*)&WtL[k*128 + cg*4];
      *(float4*)&bL[4] = *(const float4*)&WtL[k*128 + 64 + cg*4];
      *(float4*)&bR[0] = *(const float4*)&WtR[k*128 + cg*4];
      *(float4*)&bR[4] = *(const float4*)&WtR[k*128 + 64 + cg*4];
#pragma unroll
      for (int j = 0; j < 4; ++j){
#pragma unroll
        for (int u = 0; u < 8; ++u) accL[j][u] = fmaf(aa[j], bL[u], accL[j][u]);
#pragma unroll
        for (int u = 0; u < 8; ++u) accR[j][u] = fmaf(aa[j], bR[u], accR[j][u]);
      }
    }
  }
  float bvL[8], bvR[8];
  *(float4*)&bvL[0] = *(const float4*)&b_l[cg*4];
  *(float4*)&bvL[4] = *(const float4*)&b_l[64 + cg*4];
  *(float4*)&bvR[0] = *(const float4*)&b_r[cg*4];
  *(float4*)&bvR[4] = *(const float4*)&b_r[64 + cg*4];
#pragma unroll
  for (int j = 0; j < 4; ++j){
    int row = r0 + eg*4 + j;
    if (row < n){
      float oL[8], oR[8];
#pragma unroll
      for (int u = 0; u < 8; ++u){ oL[u] = accL[j][u] + bvL[u]; oR[u] = accR[j][u] + bvR[u]; }
      *(float4*)&xl[row*DD + cg*4]      = *(const float4*)&oL[0];
      *(float4*)&xl[row*DD + 64 + cg*4] = *(const float4*)&oL[4];
      *(float4*)&xr[row*DD + cg*4]      = *(const float4*)&oR[0];
      *(float4*)&xr[row*DD + 64 + cg*4] = *(const float4*)&oR[4];
    }
  }
}

// --------- per-edge score: e_emb = ea@W_edge (fused), score = lrelu(e).att ---------
// EXACT round-9 body (proven 305us, 3 blocks/CU)
__global__ __launch_bounds__(256)
void k_edge(const float* __restrict__ edge_attr, const float* __restrict__ W_edge,
            const int* __restrict__ ei, const float* __restrict__ xl,
            const float* __restrict__ xr, const float* __restrict__ att,
            const int* __restrict__ off, int* __restrict__ pos,
            uint2* __restrict__ rec, float* __restrict__ asum_mid)
{
  __shared__ __align__(16) float ea[64*EA_LD];
  __shared__ __align__(16) float Wt[32*128];
  const int tid = threadIdx.x;
  const int e0 = blockIdx.x * 64;   // E divisible by 64
  const int eg = tid >> 4;
  const int cg = tid & 15;
  // hoisted epilogue indices (removes L2 dependency from the tail chain)
  int dsts[4], srcs[4];
#pragma unroll
  for (int j = 0; j < 4; ++j){
    int e = e0 + eg*4 + j;
    srcs[j] = ei[e];
    dsts[j] = ei[E_EDGES + e];
  }
  {
    const int q = tid & 63, eb = tid >> 6;
#pragma unroll
    for (int i = 0; i < 16; ++i){
      int e = eb + 4*i;
      *(float2*)&ea[e*EA_LD + q*2] = *(const float2*)&edge_attr[(e0+e)*DD + q*2];
    }
  }
  float acc[4][8];
#pragma unroll
  for (int j = 0; j < 4; ++j)
#pragma unroll
    for (int u = 0; u < 8; ++u) acc[j][u] = 0.f;

  for (int kq = 0; kq < 4; ++kq){
    __syncthreads();
    {
      const int c4 = tid & 31, kb = tid >> 5;
#pragma unroll
      for (int i = 0; i < 4; ++i){
        int kk = kb + 8*i;
        *(float4*)&Wt[kk*128 + c4*4] = *(const float4*)&W_edge[(kq*32+kk)*DD + c4*4];
      }
    }
    __syncthreads();
    const int kb2 = kq*32;
#pragma unroll 4
    for (int k = 0; k < 32; ++k){
      float aa[4];
#pragma unroll
      for (int j = 0; j < 4; ++j) aa[j] = ea[(eg*4+j)*EA_LD + kb2 + k];
      float bb[8];
      *(float4*)&bb[0] = *(const float4*)&Wt[k*128 + cg*4];
      *(float4*)&bb[4] = *(const float4*)&Wt[k*128 + 64 + cg*4];
#pragma unroll
      for (int j = 0; j < 4; ++j)
#pragma unroll
        for (int u = 0; u < 8; ++u) acc[j][u] = fmaf(aa[j], bb[u], acc[j][u]);
    }
  }
  // epilogue: add xl[src] + xr[dst], leaky-relu, dot with att, reduce over cg
  float attv[8];
  *(float4*)&attv[0] = *(const float4*)&att[cg*4];
  *(float4*)&attv[4] = *(const float4*)&att[64 + cg*4];
  float sp[4];
#pragma unroll
  for (int j = 0; j < 4; ++j){
    float xlv[8], xrv[8];
    *(float4*)&xlv[0] = *(const float4*)&xl[srcs[j]*DD + cg*4];
    *(float4*)&xlv[4] = *(const float4*)&xl[srcs[j]*DD + 64 + cg*4];
    *(float4*)&xrv[0] = *(const float4*)&xr[dsts[j]*DD + cg*4];
    *(float4*)&xrv[4] = *(const float4*)&xr[dsts[j]*DD + 64 + cg*4];
    float p = 0.f;
#pragma unroll
    for (int u = 0; u < 8; ++u){
      float vv = acc[j][u] + xlv[u] + xrv[u];
      p += lrelu(vv) * attv[u];
    }
    sp[j] = p;
  }
#pragma unroll
  for (int m = 1; m < 16; m <<= 1){
#pragma unroll
    for (int j = 0; j < 4; ++j) sp[j] += __shfl_xor(sp[j], m);
  }
  if (cg == 0){
#pragma unroll
    for (int j = 0; j < 4; ++j){
      int d = dsts[j];
      int p = atomicAdd(&pos[d], 1);
      uint2 r;
      r.x = (unsigned)srcs[j];
      r.y = __float_as_uint(sp[j]);
      rec[off[d] + p] = r;
    }
  }
  // fused edge_attr column-sum partials (for mean_attr)
  if (tid < 128){
    float s = 0.f;
    for (int e = 0; e < 64; ++e) s += ea[e*EA_LD + tid];
    atomicAdd(&asum_mid[(blockIdx.x & 63)*DD + tid], s);
  }
}

// ---------------- me = (col_sum/E) @ W_edge ----------------
__global__ __launch_bounds__(128)
void k_me(const float* __restrict__ asum_mid, const float* __restrict__ W_edge,
          float* __restrict__ me)
{
  __shared__ float mean[128];
  const int d = threadIdx.x;
  float s = 0.f;
  for (int r = 0; r < 64; ++r) s += asum_mid[r*DD + d];
  mean[d] = s / (float)E_EDGES;
  __syncthreads();
  float acc = 0.f;
  for (int k = 0; k < 128; ++k) acc += mean[k] * W_edge[k*DD + d];
  me[d] = acc;
}

// ---------------- in-degree histogram ----------------
__global__ __launch_bounds__(256)
void k_hist(const int* __restrict__ ei, int* __restrict__ indeg)
{
  int e = blockIdx.x*256 + threadIdx.x;
  if (e < E_EDGES) atomicAdd(&indeg[ei[E_EDGES + e]], 1);
}

// ---------------- codebook squared-norms (once; bit-identical to rvq's cc) ----------------
__global__ __launch_bounds__(256)
void k_cbsq(const float* __restrict__ codebooks, double* __restrict__ cbsqd)
{
  const int tid = threadIdx.x;
  const int cl = tid >> 2, dq = tid & 3;
  const int code = blockIdx.x*64 + cl;     // 24 blocks x 64 codes = 1536
  const float4* cp = (const float4*)&codebooks[(size_t)code*DD + dq*32];
  double cc = 0.0;
#pragma unroll
  for (int i = 0; i < 8; ++i){
    float4 cv = cp[i];
    cc += (double)cv.x*cv.x + (double)cv.y*cv.y + (double)cv.z*cv.z + (double)cv.w*cv.w;
  }
  cc += __shfl_xor(cc, 1); cc += __shfl_xor(cc, 2);
  if (dq == 0) cbsqd[code] = cc;
}

// ---------------- parallel scan: 98 blocks x 512 ----------------
#define SC_NB ((N_NODES + 511) / 512)
__global__ __launch_bounds__(512)
void k_scan1(const int* __restrict__ indeg, int* __restrict__ off, int* __restrict__ bsum)
{
  __shared__ int s[512];
  const int tid = threadIdx.x;
  const int gid = blockIdx.x*512 + tid;
  int v = (gid < N_NODES) ? indeg[gid] : 0;
  s[tid] = v;
  __syncthreads();
  for (int d = 1; d < 512; d <<= 1){
    int t = (tid >= d) ? s[tid-d] : 0;
    __syncthreads();
    s[tid] += t;
    __syncthreads();
  }
  if (gid < N_NODES) off[gid] = s[tid] - v;
  if (tid == 511) bsum[blockIdx.x] = s[511];
}

__global__ __launch_bounds__(128)
void k_scan2(const int* __restrict__ bsum, int* __restrict__ boff)
{
  __shared__ int s[128];
  const int tid = threadIdx.x;
  int v = (tid < SC_NB) ? bsum[tid] : 0;
  s[tid] = v;
  __syncthreads();
  for (int d = 1; d < 128; d <<= 1){
    int t = (tid >= d) ? s[tid-d] : 0;
    __syncthreads();
    s[tid] += t;
    __syncthreads();
  }
  if (tid < SC_NB) boff[tid] = s[tid] - v;
}

__global__ __launch_bounds__(512)
void k_scan3(int* __restrict__ off, const int* __restrict__ boff)
{
  const int gid = blockIdx.x*512 + threadIdx.x;
  if (gid < N_NODES) off[gid] += boff[blockIdx.x];
  if (gid == 0) off[N_NODES] = E_EDGES;
}

// ------- per-node softmax-aggregate: 4 nodes/wave (16-lane quarters, 2xfloat4/lane) -------
__global__ __launch_bounds__(256)
void k_aggregate(const int* __restrict__ off, const uint2* __restrict__ rec,
                 const float* __restrict__ xl, const float* __restrict__ xr,
                 const float* __restrict__ me, const float* __restrict__ att,
                 const float* __restrict__ conv_bias, const int* __restrict__ batch_vec,
                 float* __restrict__ gsum, float* __restrict__ gcnt)
{
  __shared__ float hshare[16][128];
  __shared__ int bsh[16];
  const int tid = threadIdx.x, lane = tid & 63, w = tid >> 6;
  const int q4 = lane >> 4, l16 = lane & 15;
  const int node_slot = w*4 + q4;            // 0..15
  const int i = blockIdx.x*16 + node_slot;   // 3125*16 == N exactly
  const int sbase = lane & 48;               // 16-lane group base for shfl

  float xli[8], xri[8], mev[8], attv[8];
  *(float4*)&xli[0] = *(const float4*)&xl[(size_t)i*DD + l16*8];
  *(float4*)&xli[4] = *(const float4*)&xl[(size_t)i*DD + l16*8 + 4];
  *(float4*)&xri[0] = *(const float4*)&xr[(size_t)i*DD + l16*8];
  *(float4*)&xri[4] = *(const float4*)&xr[(size_t)i*DD + l16*8 + 4];
  *(float4*)&mev[0] = *(const float4*)&me[l16*8];
  *(float4*)&mev[4] = *(const float4*)&me[l16*8 + 4];
  *(float4*)&attv[0] = *(const float4*)&att[l16*8];
  *(float4*)&attv[4] = *(const float4*)&att[l16*8 + 4];
  float p = 0.f;
#pragma unroll
  for (int u = 0; u < 8; ++u) p += lrelu(xli[u] + xri[u] + mev[u]) * attv[u];
  float s_self = wsum16(p);
  const int o0 = off[i], o1 = off[i+1];
  const int deg = o1 - o0;
  // pass 1: max (first 16 records held in registers)
  uint2 myrec = make_uint2(0u, __float_as_uint(-INFINITY));
  float m = s_self;
  if (l16 < deg) myrec = rec[o0 + l16];
  m = fmaxf(m, __uint_as_float(myrec.y));
  for (int b = 16; b < deg; b += 16){
    int j = b + l16;
    if (j < deg) m = fmaxf(m, __uint_as_float(rec[o0 + j].y));
  }
  m = wmax16(m);
  // pass 2
  float wse = __expf(s_self - m);
  float den = wse;
  float a[8];
#pragma unroll
  for (int u = 0; u < 8; ++u) a[u] = wse * xli[u];
  if (deg <= 16){
    float msc = __uint_as_float(myrec.y);
    int msrc = (int)myrec.x;
#pragma unroll 4
    for (int j = 0; j < deg; ++j){
      float sc = __shfl(msc, sbase + j);
      int s = __shfl(msrc, sbase + j);
      float w_ = __expf(sc - m);
      den += w_;
      float xs[8];
      *(float4*)&xs[0] = *(const float4*)&xl[(size_t)s*DD + l16*8];
      *(float4*)&xs[4] = *(const float4*)&xl[(size_t)s*DD + l16*8 + 4];
#pragma unroll
      for (int u = 0; u < 8; ++u) a[u] = fmaf(w_, xs[u], a[u]);
    }
  } else {
#pragma unroll 4
    for (int j = 0; j < deg; ++j){
      uint2 r = rec[o0 + j];          // uniform within 16-lane group -> broadcast load
      float w_ = __expf(__uint_as_float(r.y) - m);
      den += w_;
      float xs[8];
      *(float4*)&xs[0] = *(const float4*)&xl[(size_t)(int)r.x*DD + l16*8];
      *(float4*)&xs[4] = *(const float4*)&xl[(size_t)(int)r.x*DD + l16*8 + 4];
#pragma unroll
      for (int u = 0; u < 8; ++u) a[u] = fmaf(w_, xs[u], a[u]);
    }
  }
  float inv = 1.0f / (den + 1e-16f);
  float cb8[8], hv[8];
  *(float4*)&cb8[0] = *(const float4*)&conv_bias[l16*8];
  *(float4*)&cb8[4] = *(const float4*)&conv_bias[l16*8 + 4];
#pragma unroll
  for (int u = 0; u < 8; ++u) hv[u] = a[u]*inv + cb8[u];
  const int b = batch_vec[i];
  *(float4*)&hshare[node_slot][l16*8]     = *(const float4*)&hv[0];
  *(float4*)&hshare[node_slot][l16*8 + 4] = *(const float4*)&hv[4];
  if (l16 == 0) bsh[node_slot] = b;
  __syncthreads();
  bool uni = true;
#pragma unroll
  for (int k = 1; k < 16; ++k) uni = uni && (bsh[k] == bsh[0]);
  if (uni){
    if (tid < 128){
      float s = 0.f;
#pragma unroll
      for (int k = 0; k < 16; ++k) s += hshare[k][tid];
      atomicAdd(&gsum[bsh[0]*DD + tid], s);
    }
    if (tid == 0) atomicAdd(&gcnt[bsh[0]], 16.0f);
  } else {
#pragma unroll
    for (int u = 0; u < 8; ++u)
      atomicAdd(&gsum[b*DD + l16*8 + u], hv[u]);
    if (l16 == 0) atomicAdd(&gcnt[b], 1.0f);
  }
}

// ------- residual VQ with fused pool+adapter+LN and precomputed cb norms -------
__global__ __launch_bounds__(256)
void k_rvq(const float* __restrict__ gsum, const float* __restrict__ gcnt,
           const float* __restrict__ aW, const float* __restrict__ ab,
           const float* __restrict__ ng, const float* __restrict__ nb,
           const double* __restrict__ cbsqd, const float* __restrict__ codebooks,
           float* __restrict__ ind_out, int* __restrict__ idx_i,
           float* __restrict__ accs)
{
  __shared__ __align__(16) float r_lds[128];
  __shared__ float red[128];
  __shared__ float row[128];
  __shared__ double bd[64];
  __shared__ int bi[64];
  __shared__ int chosen;
  const int g = blockIdx.x, tid = threadIdx.x;

  // ---- pool + adapter + layernorm (identical math to old k_pool) ----
  if (tid < 128){
    float denom = fmaxf(gcnt[g], 1.0f);
    row[tid] = gsum[g*DD + tid] / denom;
  }
  __syncthreads();
  float aval = 0.f;
  if (tid < 128){
    double accd = (double)ab[tid];
    for (int k = 0; k < 128; ++k) accd += (double)row[k] * (double)aW[k*DD + tid];
    aval = (float)accd;
    red[tid] = aval;
  }
  __syncthreads();
  for (int s = 64; s > 0; s >>= 1){ if (tid < s) red[tid] += red[tid+s]; __syncthreads(); }
  float mean = red[0] / 128.f; __syncthreads();
  float cdev = aval - mean;
  if (tid < 128) red[tid] = cdev*cdev;
  __syncthreads();
  for (int s = 64; s > 0; s >>= 1){ if (tid < s) red[tid] += red[tid+s]; __syncthreads(); }
  float var = red[0] / 128.f; __syncthreads();
  float linv = (float)(1.0 / sqrt((double)var + (double)LN_EPS));
  if (tid < 128) r_lds[tid] = cdev * linv * ng[tid] + nb[tid];
  __syncthreads();

  // ---- residual VQ ----
  const int cl = tid >> 2, dq = tid & 3;
  for (int q = 0; q < Q_QUANT; ++q){
    const float* cb = codebooks + (size_t)q * K_CODES * DD;
    const double* cbs = cbsqd + (size_t)q * K_CODES;
    double bestd = 1e300; int besti = 1 << 30;
    for (int r = 0; r < 8; ++r){
      int c = r*64 + cl;
      double rc = 0.0;
      const float4* cp = (const float4*)&cb[c*DD + dq*32];
      const float4* rp = (const float4*)&r_lds[dq*32];
#pragma unroll
      for (int i = 0; i < 8; ++i){
        float4 cv = cp[i]; float4 rv = rp[i];
        rc += (double)cv.x*rv.x + (double)cv.y*rv.y + (double)cv.z*rv.z + (double)cv.w*rv.w;
      }
      rc += __shfl_xor(rc, 1); rc += __shfl_xor(rc, 2);
      if (dq == 0){
        double d2 = cbs[c] - 2.0*rc;
        if (d2 < bestd || (d2 == bestd && c < besti)){ bestd = d2; besti = c; }
      }
    }
    if (dq == 0){ bd[cl] = bestd; bi[cl] = besti; }
    __syncthreads();
    if (tid < 64){
      double d2 = bd[tid]; int ii = bi[tid];
#pragma unroll
      for (int m = 1; m < 64; m <<= 1){
        double od = __shfl_xor(d2, m); int oi = __shfl_xor(ii, m);
        if (od < d2 || (od == d2 && oi < ii)){ d2 = od; ii = oi; }
      }
      if (tid == 0) chosen = ii;
    }
    __syncthreads();
    const int idx = chosen;
    if (tid == 0){
      ind_out[g*Q_QUANT + q] = (float)idx;
      idx_i[g*Q_QUANT + q] = idx;
    }
    if (tid < 128){
      float cd = cb[idx*DD + tid];
      float diff = cd - r_lds[tid];
      red[tid] = diff * diff;
      r_lds[tid] -= cd;
    }
    __syncthreads();
    for (int s = 64; s > 0; s >>= 1){ if (tid < s) red[tid] += red[tid+s]; __syncthreads(); }
    if (tid == 0) atomicAdd(&accs[q], red[0]);
    __syncthreads();
  }
  if (tid < 128) red[tid] = r_lds[tid]*r_lds[tid];
  __syncthreads();
  for (int s = 64; s > 0; s >>= 1){ if (tid < s) red[tid] += red[tid+s]; __syncthreads(); }
  if (tid == 0) atomicAdd(&accs[3], red[0]);
}

// ---------------- tokens: LN(code @ out_W + out_b); block 0 also writes loss ----------------
__global__ __launch_bounds__(256)
void k_tokens(const float* __restrict__ codebooks, const int* __restrict__ idx_i,
              const float* __restrict__ out_W, const float* __restrict__ out_b,
              const float* __restrict__ og, const float* __restrict__ ob,
              const float* __restrict__ accs,
              float* __restrict__ tokens, float* __restrict__ loss_out)
{
  __shared__ __align__(16) float c_lds[128];
  __shared__ float red[256];
  const int blk = blockIdx.x;
  const int g = blk / 3, q = blk % 3;
  const int tid = threadIdx.x;
  if (blk == 0 && tid == 0){
    float commit = (accs[0] + accs[1] + accs[2]) / (3.0f * G_GRAPHS * DD);
    float resid  = accs[3] / ((float)G_GRAPHS * DD);
    loss_out[0] = commit + resid;
  }
  const int idx = idx_i[g*Q_QUANT + q];
  if (tid < 128) c_lds[tid] = codebooks[((size_t)q*K_CODES + idx)*DD + tid];
  __syncthreads();
  double v0 = (double)out_b[tid];
  double v1 = (double)out_b[tid + 256];
  for (int k = 0; k < 128; ++k){
    double ck = (double)c_lds[k];
    v0 += ck * (double)out_W[k*FD_OUT + tid];
    v1 += ck * (double)out_W[k*FD_OUT + tid + 256];
  }
  float f0 = (float)v0, f1 = (float)v1;
  red[tid] = f0 + f1; __syncthreads();
  for (int s = 128; s > 0; s >>= 1){ if (tid < s) red[tid] += red[tid+s]; __syncthreads(); }
  float mean = red[0] / 512.f; __syncthreads();
  float d0 = f0 - mean, d1 = f1 - mean;
  red[tid] = d0*d0 + d1*d1; __syncthreads();
  for (int s = 128; s > 0; s >>= 1){ if (tid < s) red[tid] += red[tid+s]; __syncthreads(); }
  float var = red[0] / 512.f; __syncthreads();
  float inv = (float)(1.0 / sqrt((double)var + (double)LN_EPS));
  tokens[(size_t)blk*FD_OUT + tid]       = d0*inv*og[tid] + ob[tid];
  tokens[(size_t)blk*FD_OUT + tid + 256] = d1*inv*og[tid+256] + ob[tid+256];
}

extern "C" void kernel_launch(void* const* d_in, const int* in_sizes, int n_in,
                              void* d_out, int out_size, void* d_ws, size_t ws_size,
                              hipStream_t stream)
{
  (void)in_sizes; (void)n_in; (void)out_size; (void)ws_size;
  const float* x         = (const float*)d_in[0];
  const int*   ei        = (const int*)d_in[1];
  const float* edge_attr = (const float*)d_in[2];
  const int*   batch_vec = (const int*)d_in[3];
  const float* W_l       = (const float*)d_in[4];
  const float* b_l       = (const float*)d_in[5];
  const float* W_r       = (const float*)d_in[6];
  const float* b_r       = (const float*)d_in[7];
  const float* W_edge    = (const float*)d_in[8];
  const float* att       = (const float*)d_in[9];
  const float* conv_bias = (const float*)d_in[10];
  const float* aW        = (const float*)d_in[11];
  const float* ab        = (const float*)d_in[12];
  const float* ng        = (const float*)d_in[13];
  const float* nb        = (const float*)d_in[14];
  const float* codebooks = (const float*)d_in[15];
  const float* out_W     = (const float*)d_in[16];
  const float* out_b     = (const float*)d_in[17];
  const float* og        = (const float*)d_in[18];
  const float* ob        = (const float*)d_in[19];
  float* outf = (float*)d_out;

  char* w = (char*)d_ws;
  size_t o = 0;
  auto nxt = [&](size_t bytes)->void*{
    void* p = w + o;
    o += (bytes + 511) & ~(size_t)511;
    return p;
  };
  // --- zeroed buffers first (single memset over the span) ---
  int*   indeg    = (int*)  nxt((size_t)N_NODES*4);
  int*   pos      = (int*)  nxt((size_t)N_NODES*4);
  float* asum_mid = (float*)nxt((size_t)64*DD*4);
  float* gsum     = (float*)nxt((size_t)G_GRAPHS*DD*4);
  float* gcnt     = (float*)nxt((size_t)G_GRAPHS*4);
  float* accs     = (float*)nxt(16);
  const size_t zero_span = o;
  // --- non-zeroed ---
  int*   off      = (int*)  nxt((size_t)(N_NODES+1)*4);
  float* xl       = (float*)nxt((size_t)N_NODES*DD*4);
  float* xr       = (float*)nxt((size_t)N_NODES*DD*4);
  uint2* rec      = (uint2*)nxt((size_t)E_EDGES*8);
  float* me       = (float*)nxt((size_t)DD*4);
  int*   idx_i    = (int*)  nxt((size_t)G_GRAPHS*Q_QUANT*4);
  int*   bsum     = (int*)  nxt((size_t)SC_NB*4);
  int*   boff     = (int*)  nxt((size_t)SC_NB*4);
  double* cbsqd   = (double*)nxt((size_t)Q_QUANT*K_CODES*8);

  hipMemsetAsync(w, 0, zero_span, stream);

  k_cbsq<<<dim3(Q_QUANT*K_CODES/64), dim3(256), 0, stream>>>(codebooks, cbsqd);
  k_hist<<<dim3((E_EDGES+255)/256), dim3(256), 0, stream>>>(ei, indeg);
  k_scan1<<<dim3(SC_NB), dim3(512), 0, stream>>>(indeg, off, bsum);
  k_scan2<<<dim3(1), dim3(128), 0, stream>>>(bsum, boff);
  k_scan3<<<dim3(SC_NB), dim3(512), 0, stream>>>(off, boff);
  k_xform2<<<dim3((N_NODES+63)/64), dim3(256), 0, stream>>>(x, W_l, b_l, W_r, b_r,
                                                            xl, xr, N_NODES);
  k_edge<<<dim3(E_EDGES/64), dim3(256), 0, stream>>>(edge_attr, W_edge, ei, xl, xr, att,
                                                     off, pos, rec, asum_mid);
  k_me<<<dim3(1), dim3(128), 0, stream>>>(asum_mid, W_edge, me);
  k_aggregate<<<dim3(N_NODES/16), dim3(256), 0, stream>>>(off, rec, xl, xr, me, att,
                                                          conv_bias, batch_vec, gsum, gcnt);
  k_rvq<<<dim3(G_GRAPHS), dim3(256), 0, stream>>>(gsum, gcnt, aW, ab, ng, nb, cbsqd,
                                                  codebooks,
                                                  outf + (size_t)G_GRAPHS*Q_QUANT*FD_OUT,
                                                  idx_i, accs);
  k_tokens<<<dim3(G_GRAPHS*Q_QUANT), dim3(256), 0, stream>>>(codebooks, idx_i, out_W, out_b,
                                                             og, ob, accs, outf,
                                                             outf + (size_t)G_GRAPHS*Q_QUANT*FD_OUT
                                                                  + (size_t)G_GRAPHS*Q_QUANT);
}

// Round 14
// 568.728 us; speedup vs baseline: 1.0562x; 1.0562x over previous
//
#include <hip/hip_runtime.h>
#include <math.h>

#define N_NODES 50000
#define E_EDGES 600000
#define DD 128
#define G_GRAPHS 512
#define K_CODES 512
#define Q_QUANT 3
#define FD_OUT 512
#define NEG_SLOPE 0.2f
#define LN_EPS 1e-5f

static __device__ __forceinline__ float lrelu(float v){ return v > 0.f ? v : NEG_SLOPE*v; }
static __device__ __forceinline__ float wsum32(float v){
#pragma unroll
  for (int m = 1; m < 32; m <<= 1) v += __shfl_xor(v, m);
  return v;
}
static __device__ __forceinline__ float wmax32(float v){
#pragma unroll
  for (int m = 1; m < 32; m <<= 1) v = fmaxf(v, __shfl_xor(v, m));
  return v;
}

#define EA_LD 130   // row pitch: 520B -> A-broadcast addrs land on distinct banks

// ---------------- fused transform: xl = x@W_l + b_l ; xr = x@W_r + b_r ----------------
// (unchanged — proven)
__global__ __launch_bounds__(256)
void k_xform2(const float* __restrict__ x,
              const float* __restrict__ W_l, const float* __restrict__ b_l,
              const float* __restrict__ W_r, const float* __restrict__ b_r,
              float* __restrict__ xl, float* __restrict__ xr, int n)
{
  __shared__ __align__(16) float xt[64*EA_LD];
  __shared__ __align__(16) float WtL[32*128];
  __shared__ __align__(16) float WtR[32*128];
  const int tid = threadIdx.x;
  const int r0 = blockIdx.x * 64;
  {
    const int q = tid & 63, eb = tid >> 6;
#pragma unroll
    for (int i = 0; i < 16; ++i){
      int e = eb + 4*i;
      int row = r0 + e;
      float2 v = make_float2(0.f, 0.f);
      if (row < n) v = *(const float2*)&x[row*DD + q*2];
      *(float2*)&xt[e*EA_LD + q*2] = v;
    }
  }
  const int eg = tid >> 4;
  const int cg = tid & 15;
  float accL[4][8], accR[4][8];
#pragma unroll
  for (int j = 0; j < 4; ++j)
#pragma unroll
    for (int u = 0; u < 8; ++u){ accL[j][u] = 0.f; accR[j][u] = 0.f; }

  for (int kq = 0; kq < 4; ++kq){
    __syncthreads();
    {
      const int c4 = tid & 31, kb = tid >> 5;
#pragma unroll
      for (int i = 0; i < 4; ++i){
        int kk = kb + 8*i;
        *(float4*)&WtL[kk*128 + c4*4] = *(const float4*)&W_l[(kq*32+kk)*DD + c4*4];
        *(float4*)&WtR[kk*128 + c4*4] = *(const float4*)&W_r[(kq*32+kk)*DD + c4*4];
      }
    }
    __syncthreads();
    const int kb2 = kq*32;
#pragma unroll 4
    for (int k = 0; k < 32; ++k){
      float aa[4];
#pragma unroll
      for (int j = 0; j < 4; ++j) aa[j] = xt[(eg*4+j)*EA_LD + kb2 + k];
      float bL[8], bR[8];
      *(float4*)&bL[0] = *(const float4*)&WtL[k*128 + cg*4];
      *(float4*)&bL[4] = *(const float4*)&WtL[k*128 + 64 + cg*4];
      *(float4*)&bR[0] = *(const float4*)&WtR[k*128 + cg*4];
      *(float4*)&bR[4] = *(const float4*)&WtR[k*128 + 64 + cg*4];
#pragma unroll
      for (int j = 0; j < 4; ++j){
#pragma unroll
        for (int u = 0; u < 8; ++u) accL[j][u] = fmaf(aa[j], bL[u], accL[j][u]);
#pragma unroll
        for (int u = 0; u < 8; ++u) accR[j][u] = fmaf(aa[j], bR[u], accR[j][u]);
      }
    }
  }
  float bvL[8], bvR[8];
  *(float4*)&bvL[0] = *(const float4*)&b_l[cg*4];
  *(float4*)&bvL[4] = *(const float4*)&b_l[64 + cg*4];
  *(float4*)&bvR[0] = *(const float4*)&b_r[cg*4];
  *(float4*)&bvR[4] = *(const float4*)&b_r[64 + cg*4];
#pragma unroll
  for (int j = 0; j < 4; ++j){
    int row = r0 + eg*4 + j;
    if (row < n){
      float oL[8], oR[8];
#pragma unroll
      for (int u = 0; u < 8; ++u){ oL[u] = accL[j][u] + bvL[u]; oR[u] = accR[j][u] + bvR[u]; }
      *(float4*)&xl[row*DD + cg*4]      = *(const float4*)&oL[0];
      *(float4*)&xl[row*DD + 64 + cg*4] = *(const float4*)&oL[4];
      *(float4*)&xr[row*DD + cg*4]      = *(const float4*)&oR[0];
      *(float4*)&xr[row*DD + 64 + cg*4] = *(const float4*)&oR[4];
    }
  }
}

// --------- per-edge score: e_emb = ea@W_edge (fused), score = lrelu(e).att ---------
// EXACT round-9 body (proven 305us, 3 blocks/CU)
__global__ __launch_bounds__(256)
void k_edge(const float* __restrict__ edge_attr, const float* __restrict__ W_edge,
            const int* __restrict__ ei, const float* __restrict__ xl,
            const float* __restrict__ xr, const float* __restrict__ att,
            const int* __restrict__ off, int* __restrict__ pos,
            uint2* __restrict__ rec, float* __restrict__ asum_mid)
{
  __shared__ __align__(16) float ea[64*EA_LD];
  __shared__ __align__(16) float Wt[32*128];
  const int tid = threadIdx.x;
  const int e0 = blockIdx.x * 64;   // E divisible by 64
  const int eg = tid >> 4;
  const int cg = tid & 15;
  // hoisted epilogue indices (removes L2 dependency from the tail chain)
  int dsts[4], srcs[4];
#pragma unroll
  for (int j = 0; j < 4; ++j){
    int e = e0 + eg*4 + j;
    srcs[j] = ei[e];
    dsts[j] = ei[E_EDGES + e];
  }
  {
    const int q = tid & 63, eb = tid >> 6;
#pragma unroll
    for (int i = 0; i < 16; ++i){
      int e = eb + 4*i;
      *(float2*)&ea[e*EA_LD + q*2] = *(const float2*)&edge_attr[(e0+e)*DD + q*2];
    }
  }
  float acc[4][8];
#pragma unroll
  for (int j = 0; j < 4; ++j)
#pragma unroll
    for (int u = 0; u < 8; ++u) acc[j][u] = 0.f;

  for (int kq = 0; kq < 4; ++kq){
    __syncthreads();
    {
      const int c4 = tid & 31, kb = tid >> 5;
#pragma unroll
      for (int i = 0; i < 4; ++i){
        int kk = kb + 8*i;
        *(float4*)&Wt[kk*128 + c4*4] = *(const float4*)&W_edge[(kq*32+kk)*DD + c4*4];
      }
    }
    __syncthreads();
    const int kb2 = kq*32;
#pragma unroll 4
    for (int k = 0; k < 32; ++k){
      float aa[4];
#pragma unroll
      for (int j = 0; j < 4; ++j) aa[j] = ea[(eg*4+j)*EA_LD + kb2 + k];
      float bb[8];
      *(float4*)&bb[0] = *(const float4*)&Wt[k*128 + cg*4];
      *(float4*)&bb[4] = *(const float4*)&Wt[k*128 + 64 + cg*4];
#pragma unroll
      for (int j = 0; j < 4; ++j)
#pragma unroll
        for (int u = 0; u < 8; ++u) acc[j][u] = fmaf(aa[j], bb[u], acc[j][u]);
    }
  }
  // epilogue: add xl[src] + xr[dst], leaky-relu, dot with att, reduce over cg
  float attv[8];
  *(float4*)&attv[0] = *(const float4*)&att[cg*4];
  *(float4*)&attv[4] = *(const float4*)&att[64 + cg*4];
  float sp[4];
#pragma unroll
  for (int j = 0; j < 4; ++j){
    float xlv[8], xrv[8];
    *(float4*)&xlv[0] = *(const float4*)&xl[srcs[j]*DD + cg*4];
    *(float4*)&xlv[4] = *(const float4*)&xl[srcs[j]*DD + 64 + cg*4];
    *(float4*)&xrv[0] = *(const float4*)&xr[dsts[j]*DD + cg*4];
    *(float4*)&xrv[4] = *(const float4*)&xr[dsts[j]*DD + 64 + cg*4];
    float p = 0.f;
#pragma unroll
    for (int u = 0; u < 8; ++u){
      float vv = acc[j][u] + xlv[u] + xrv[u];
      p += lrelu(vv) * attv[u];
    }
    sp[j] = p;
  }
#pragma unroll
  for (int m = 1; m < 16; m <<= 1){
#pragma unroll
    for (int j = 0; j < 4; ++j) sp[j] += __shfl_xor(sp[j], m);
  }
  if (cg == 0){
#pragma unroll
    for (int j = 0; j < 4; ++j){
      int d = dsts[j];
      int p = atomicAdd(&pos[d], 1);
      uint2 r;
      r.x = (unsigned)srcs[j];
      r.y = __float_as_uint(sp[j]);
      rec[off[d] + p] = r;
    }
  }
  // fused edge_attr column-sum partials (for mean_attr)
  if (tid < 128){
    float s = 0.f;
    for (int e = 0; e < 64; ++e) s += ea[e*EA_LD + tid];
    atomicAdd(&asum_mid[(blockIdx.x & 63)*DD + tid], s);
  }
}

// ---------------- me = (col_sum/E) @ W_edge ----------------
__global__ __launch_bounds__(128)
void k_me(const float* __restrict__ asum_mid, const float* __restrict__ W_edge,
          float* __restrict__ me)
{
  __shared__ float mean[128];
  const int d = threadIdx.x;
  float s = 0.f;
  for (int r = 0; r < 64; ++r) s += asum_mid[r*DD + d];
  mean[d] = s / (float)E_EDGES;
  __syncthreads();
  float acc = 0.f;
  for (int k = 0; k < 128; ++k) acc += mean[k] * W_edge[k*DD + d];
  me[d] = acc;
}

// ---------------- in-degree histogram ----------------
__global__ __launch_bounds__(256)
void k_hist(const int* __restrict__ ei, int* __restrict__ indeg)
{
  int e = blockIdx.x*256 + threadIdx.x;
  if (e < E_EDGES) atomicAdd(&indeg[ei[E_EDGES + e]], 1);
}

// ---------------- codebook squared-norms (once; bit-identical to rvq's cc) ----------------
__global__ __launch_bounds__(256)
void k_cbsq(const float* __restrict__ codebooks, double* __restrict__ cbsqd)
{
  const int tid = threadIdx.x;
  const int cl = tid >> 2, dq = tid & 3;
  const int code = blockIdx.x*64 + cl;     // 24 blocks x 64 codes = 1536
  const float4* cp = (const float4*)&codebooks[(size_t)code*DD + dq*32];
  double cc = 0.0;
#pragma unroll
  for (int i = 0; i < 8; ++i){
    float4 cv = cp[i];
    cc += (double)cv.x*cv.x + (double)cv.y*cv.y + (double)cv.z*cv.z + (double)cv.w*cv.w;
  }
  cc += __shfl_xor(cc, 1); cc += __shfl_xor(cc, 2);
  if (dq == 0) cbsqd[code] = cc;
}

// ---------------- parallel scan: 98 blocks x 512 ----------------
#define SC_NB ((N_NODES + 511) / 512)
__global__ __launch_bounds__(512)
void k_scan1(const int* __restrict__ indeg, int* __restrict__ off, int* __restrict__ bsum)
{
  __shared__ int s[512];
  const int tid = threadIdx.x;
  const int gid = blockIdx.x*512 + tid;
  int v = (gid < N_NODES) ? indeg[gid] : 0;
  s[tid] = v;
  __syncthreads();
  for (int d = 1; d < 512; d <<= 1){
    int t = (tid >= d) ? s[tid-d] : 0;
    __syncthreads();
    s[tid] += t;
    __syncthreads();
  }
  if (gid < N_NODES) off[gid] = s[tid] - v;
  if (tid == 511) bsum[blockIdx.x] = s[511];
}

__global__ __launch_bounds__(128)
void k_scan2(const int* __restrict__ bsum, int* __restrict__ boff)
{
  __shared__ int s[128];
  const int tid = threadIdx.x;
  int v = (tid < SC_NB) ? bsum[tid] : 0;
  s[tid] = v;
  __syncthreads();
  for (int d = 1; d < 128; d <<= 1){
    int t = (tid >= d) ? s[tid-d] : 0;
    __syncthreads();
    s[tid] += t;
    __syncthreads();
  }
  if (tid < SC_NB) boff[tid] = s[tid] - v;
}

__global__ __launch_bounds__(512)
void k_scan3(int* __restrict__ off, const int* __restrict__ boff)
{
  const int gid = blockIdx.x*512 + threadIdx.x;
  if (gid < N_NODES) off[gid] += boff[blockIdx.x];
  if (gid == 0) off[N_NODES] = E_EDGES;
}

// ------- per-node softmax-aggregate: 2 nodes/wave (32-lane halves, float4/lane) -------
__global__ __launch_bounds__(256)
void k_aggregate(const int* __restrict__ off, const uint2* __restrict__ rec,
                 const float* __restrict__ xl, const float* __restrict__ xr,
                 const float* __restrict__ me, const float* __restrict__ att,
                 const float* __restrict__ conv_bias, const int* __restrict__ batch_vec,
                 float* __restrict__ gsum, float* __restrict__ gcnt)
{
  __shared__ float hshare[8][128];
  __shared__ int bsh[8];
  const int tid = threadIdx.x, lane = tid & 63, w = tid >> 6;
  const int hh = lane >> 5, l32 = lane & 31;
  const int node_slot = w*2 + hh;            // 0..7
  const int i = blockIdx.x*8 + node_slot;    // 6250*8 == N exactly
  const int sbase = lane & 32;               // shfl base for this half

  float4 xli = *(const float4*)&xl[(size_t)i*DD + l32*4];
  float4 xri = *(const float4*)&xr[(size_t)i*DD + l32*4];
  float4 mev = *(const float4*)&me[l32*4];
  float4 attv = *(const float4*)&att[l32*4];
  float p;
  {
    float v0 = xli.x + xri.x + mev.x;
    float v1 = xli.y + xri.y + mev.y;
    float v2 = xli.z + xri.z + mev.z;
    float v3 = xli.w + xri.w + mev.w;
    p = lrelu(v0)*attv.x + lrelu(v1)*attv.y + lrelu(v2)*attv.z + lrelu(v3)*attv.w;
  }
  float s_self = wsum32(p);
  const int o0 = off[i], o1 = off[i+1];
  const int deg = o1 - o0;
  // pass 1: max (first 32 records held in registers)
  uint2 myrec = make_uint2(0u, __float_as_uint(-INFINITY));
  float m = s_self;
  if (l32 < deg) myrec = rec[o0 + l32];
  m = fmaxf(m, __uint_as_float(myrec.y));
  for (int b = 32; b < deg; b += 32){
    int j = b + l32;
    if (j < deg) m = fmaxf(m, __uint_as_float(rec[o0 + j].y));
  }
  m = wmax32(m);
  // pass 2
  float wse = __expf(s_self - m);
  float den = wse;
  float4 a;
  a.x = wse * xli.x; a.y = wse * xli.y; a.z = wse * xli.z; a.w = wse * xli.w;
  if (deg <= 32){
    float msc = __uint_as_float(myrec.y);
    int msrc = (int)myrec.x;
#pragma unroll 4
    for (int j = 0; j < deg; ++j){
      float sc = __shfl(msc, sbase + j);
      int s = __shfl(msrc, sbase + j);
      float w_ = __expf(sc - m);
      den += w_;
      float4 xs = *(const float4*)&xl[(size_t)s*DD + l32*4];
      a.x = fmaf(w_, xs.x, a.x);
      a.y = fmaf(w_, xs.y, a.y);
      a.z = fmaf(w_, xs.z, a.z);
      a.w = fmaf(w_, xs.w, a.w);
    }
  } else {
#pragma unroll 4
    for (int j = 0; j < deg; ++j){
      uint2 r = rec[o0 + j];          // uniform within half -> broadcast load
      float w_ = __expf(__uint_as_float(r.y) - m);
      den += w_;
      float4 xs = *(const float4*)&xl[(size_t)(int)r.x*DD + l32*4];
      a.x = fmaf(w_, xs.x, a.x);
      a.y = fmaf(w_, xs.y, a.y);
      a.z = fmaf(w_, xs.z, a.z);
      a.w = fmaf(w_, xs.w, a.w);
    }
  }
  float inv = 1.0f / (den + 1e-16f);
  float4 cb4 = *(const float4*)&conv_bias[l32*4];
  float4 hv;
  hv.x = a.x*inv + cb4.x;
  hv.y = a.y*inv + cb4.y;
  hv.z = a.z*inv + cb4.z;
  hv.w = a.w*inv + cb4.w;
  const int b = batch_vec[i];
  *(float4*)&hshare[node_slot][l32*4] = hv;
  if (l32 == 0) bsh[node_slot] = b;
  __syncthreads();
  bool uni = (bsh[0]==bsh[1]) && (bsh[1]==bsh[2]) && (bsh[2]==bsh[3]) &&
             (bsh[3]==bsh[4]) && (bsh[4]==bsh[5]) && (bsh[5]==bsh[6]) && (bsh[6]==bsh[7]);
  if (uni){
    if (tid < 128){
      float s = hshare[0][tid] + hshare[1][tid] + hshare[2][tid] + hshare[3][tid]
              + hshare[4][tid] + hshare[5][tid] + hshare[6][tid] + hshare[7][tid];
      atomicAdd(&gsum[bsh[0]*DD + tid], s);
    }
    if (tid == 0) atomicAdd(&gcnt[bsh[0]], 8.0f);
  } else {
    atomicAdd(&gsum[b*DD + l32*4 + 0], hv.x);
    atomicAdd(&gsum[b*DD + l32*4 + 1], hv.y);
    atomicAdd(&gsum[b*DD + l32*4 + 2], hv.z);
    atomicAdd(&gsum[b*DD + l32*4 + 3], hv.w);
    if (l32 == 0) atomicAdd(&gcnt[b], 1.0f);
  }
}

// ------- residual VQ with fused pool+adapter+LN and precomputed cb norms -------
__global__ __launch_bounds__(256)
void k_rvq(const float* __restrict__ gsum, const float* __restrict__ gcnt,
           const float* __restrict__ aW, const float* __restrict__ ab,
           const float* __restrict__ ng, const float* __restrict__ nb,
           const double* __restrict__ cbsqd, const float* __restrict__ codebooks,
           float* __restrict__ ind_out, int* __restrict__ idx_i,
           float* __restrict__ accs)
{
  __shared__ __align__(16) float r_lds[128];
  __shared__ float red[128];
  __shared__ float row[128];
  __shared__ double bd[64];
  __shared__ int bi[64];
  __shared__ int chosen;
  const int g = blockIdx.x, tid = threadIdx.x;

  // ---- pool + adapter + layernorm (identical math to old k_pool) ----
  if (tid < 128){
    float denom = fmaxf(gcnt[g], 1.0f);
    row[tid] = gsum[g*DD + tid] / denom;
  }
  __syncthreads();
  float aval = 0.f;
  if (tid < 128){
    double accd = (double)ab[tid];
    for (int k = 0; k < 128; ++k) accd += (double)row[k] * (double)aW[k*DD + tid];
    aval = (float)accd;
    red[tid] = aval;
  }
  __syncthreads();
  for (int s = 64; s > 0; s >>= 1){ if (tid < s) red[tid] += red[tid+s]; __syncthreads(); }
  float mean = red[0] / 128.f; __syncthreads();
  float cdev = aval - mean;
  if (tid < 128) red[tid] = cdev*cdev;
  __syncthreads();
  for (int s = 64; s > 0; s >>= 1){ if (tid < s) red[tid] += red[tid+s]; __syncthreads(); }
  float var = red[0] / 128.f; __syncthreads();
  float linv = (float)(1.0 / sqrt((double)var + (double)LN_EPS));
  if (tid < 128) r_lds[tid] = cdev * linv * ng[tid] + nb[tid];
  __syncthreads();

  // ---- residual VQ ----
  const int cl = tid >> 2, dq = tid & 3;
  for (int q = 0; q < Q_QUANT; ++q){
    const float* cb = codebooks + (size_t)q * K_CODES * DD;
    const double* cbs = cbsqd + (size_t)q * K_CODES;
    double bestd = 1e300; int besti = 1 << 30;
    for (int r = 0; r < 8; ++r){
      int c = r*64 + cl;
      double rc = 0.0;
      const float4* cp = (const float4*)&cb[c*DD + dq*32];
      const float4* rp = (const float4*)&r_lds[dq*32];
#pragma unroll
      for (int i = 0; i < 8; ++i){
        float4 cv = cp[i]; float4 rv = rp[i];
        rc += (double)cv.x*rv.x + (double)cv.y*rv.y + (double)cv.z*rv.z + (double)cv.w*rv.w;
      }
      rc += __shfl_xor(rc, 1); rc += __shfl_xor(rc, 2);
      if (dq == 0){
        double d2 = cbs[c] - 2.0*rc;
        if (d2 < bestd || (d2 == bestd && c < besti)){ bestd = d2; besti = c; }
      }
    }
    if (dq == 0){ bd[cl] = bestd; bi[cl] = besti; }
    __syncthreads();
    if (tid < 64){
      double d2 = bd[tid]; int ii = bi[tid];
#pragma unroll
      for (int m = 1; m < 64; m <<= 1){
        double od = __shfl_xor(d2, m); int oi = __shfl_xor(ii, m);
        if (od < d2 || (od == d2 && oi < ii)){ d2 = od; ii = oi; }
      }
      if (tid == 0) chosen = ii;
    }
    __syncthreads();
    const int idx = chosen;
    if (tid == 0){
      ind_out[g*Q_QUANT + q] = (float)idx;
      idx_i[g*Q_QUANT + q] = idx;
    }
    if (tid < 128){
      float cd = cb[idx*DD + tid];
      float diff = cd - r_lds[tid];
      red[tid] = diff * diff;
      r_lds[tid] -= cd;
    }
    __syncthreads();
    for (int s = 64; s > 0; s >>= 1){ if (tid < s) red[tid] += red[tid+s]; __syncthreads(); }
    if (tid == 0) atomicAdd(&accs[q], red[0]);
    __syncthreads();
  }
  if (tid < 128) red[tid] = r_lds[tid]*r_lds[tid];
  __syncthreads();
  for (int s = 64; s > 0; s >>= 1){ if (tid < s) red[tid] += red[tid+s]; __syncthreads(); }
  if (tid == 0) atomicAdd(&accs[3], red[0]);
}

// ---------------- tokens: LN(code @ out_W + out_b); block 0 also writes loss ----------------
__global__ __launch_bounds__(256)
void k_tokens(const float* __restrict__ codebooks, const int* __restrict__ idx_i,
              const float* __restrict__ out_W, const float* __restrict__ out_b,
              const float* __restrict__ og, const float* __restrict__ ob,
              const float* __restrict__ accs,
              float* __restrict__ tokens, float* __restrict__ loss_out)
{
  __shared__ __align__(16) float c_lds[128];
  __shared__ float red[256];
  const int blk = blockIdx.x;
  const int g = blk / 3, q = blk % 3;
  const int tid = threadIdx.x;
  if (blk == 0 && tid == 0){
    float commit = (accs[0] + accs[1] + accs[2]) / (3.0f * G_GRAPHS * DD);
    float resid  = accs[3] / ((float)G_GRAPHS * DD);
    loss_out[0] = commit + resid;
  }
  const int idx = idx_i[g*Q_QUANT + q];
  if (tid < 128) c_lds[tid] = codebooks[((size_t)q*K_CODES + idx)*DD + tid];
  __syncthreads();
  double v0 = (double)out_b[tid];
  double v1 = (double)out_b[tid + 256];
  for (int k = 0; k < 128; ++k){
    double ck = (double)c_lds[k];
    v0 += ck * (double)out_W[k*FD_OUT + tid];
    v1 += ck * (double)out_W[k*FD_OUT + tid + 256];
  }
  float f0 = (float)v0, f1 = (float)v1;
  red[tid] = f0 + f1; __syncthreads();
  for (int s = 128; s > 0; s >>= 1){ if (tid < s) red[tid] += red[tid+s]; __syncthreads(); }
  float mean = red[0] / 512.f; __syncthreads();
  float d0 = f0 - mean, d1 = f1 - mean;
  red[tid] = d0*d0 + d1*d1; __syncthreads();
  for (int s = 128; s > 0; s >>= 1){ if (tid < s) red[tid] += red[tid+s]; __syncthreads(); }
  float var = red[0] / 512.f; __syncthreads();
  float inv = (float)(1.0 / sqrt((double)var + (double)LN_EPS));
  tokens[(size_t)blk*FD_OUT + tid]       = d0*inv*og[tid] + ob[tid];
  tokens[(size_t)blk*FD_OUT + tid + 256] = d1*inv*og[tid+256] + ob[tid+256];
}

extern "C" void kernel_launch(void* const* d_in, const int* in_sizes, int n_in,
                              void* d_out, int out_size, void* d_ws, size_t ws_size,
                              hipStream_t stream)
{
  (void)in_sizes; (void)n_in; (void)out_size; (void)ws_size;
  const float* x         = (const float*)d_in[0];
  const int*   ei        = (const int*)d_in[1];
  const float* edge_attr = (const float*)d_in[2];
  const int*   batch_vec = (const int*)d_in[3];
  const float* W_l       = (const float*)d_in[4];
  const float* b_l       = (const float*)d_in[5];
  const float* W_r       = (const float*)d_in[6];
  const float* b_r       = (const float*)d_in[7];
  const float* W_edge    = (const float*)d_in[8];
  const float* att       = (const float*)d_in[9];
  const float* conv_bias = (const float*)d_in[10];
  const float* aW        = (const float*)d_in[11];
  const float* ab        = (const float*)d_in[12];
  const float* ng        = (const float*)d_in[13];
  const float* nb        = (const float*)d_in[14];
  const float* codebooks = (const float*)d_in[15];
  const float* out_W     = (const float*)d_in[16];
  const float* out_b     = (const float*)d_in[17];
  const float* og        = (const float*)d_in[18];
  const float* ob        = (const float*)d_in[19];
  float* outf = (float*)d_out;

  char* w = (char*)d_ws;
  size_t o = 0;
  auto nxt = [&](size_t bytes)->void*{
    void* p = w + o;
    o += (bytes + 511) & ~(size_t)511;
    return p;
  };
  // --- zeroed buffers first (single memset over the span) ---
  int*   indeg    = (int*)  nxt((size_t)N_NODES*4);
  int*   pos      = (int*)  nxt((size_t)N_NODES*4);
  float* asum_mid = (float*)nxt((size_t)64*DD*4);
  float* gsum     = (float*)nxt((size_t)G_GRAPHS*DD*4);
  float* gcnt     = (float*)nxt((size_t)G_GRAPHS*4);
  float* accs     = (float*)nxt(16);
  const size_t zero_span = o;
  // --- non-zeroed ---
  int*   off      = (int*)  nxt((size_t)(N_NODES+1)*4);
  float* xl       = (float*)nxt((size_t)N_NODES*DD*4);
  float* xr       = (float*)nxt((size_t)N_NODES*DD*4);
  uint2* rec      = (uint2*)nxt((size_t)E_EDGES*8);
  float* me       = (float*)nxt((size_t)DD*4);
  int*   idx_i    = (int*)  nxt((size_t)G_GRAPHS*Q_QUANT*4);
  int*   bsum     = (int*)  nxt((size_t)SC_NB*4);
  int*   boff     = (int*)  nxt((size_t)SC_NB*4);
  double* cbsqd   = (double*)nxt((size_t)Q_QUANT*K_CODES*8);

  hipMemsetAsync(w, 0, zero_span, stream);

  k_cbsq<<<dim3(Q_QUANT*K_CODES/64), dim3(256), 0, stream>>>(codebooks, cbsqd);
  k_hist<<<dim3((E_EDGES+255)/256), dim3(256), 0, stream>>>(ei, indeg);
  k_scan1<<<dim3(SC_NB), dim3(512), 0, stream>>>(indeg, off, bsum);
  k_scan2<<<dim3(1), dim3(128), 0, stream>>>(bsum, boff);
  k_scan3<<<dim3(SC_NB), dim3(512), 0, stream>>>(off, boff);
  k_xform2<<<dim3((N_NODES+63)/64), dim3(256), 0, stream>>>(x, W_l, b_l, W_r, b_r,
                                                            xl, xr, N_NODES);
  k_edge<<<dim3(E_EDGES/64), dim3(256), 0, stream>>>(edge_attr, W_edge, ei, xl, xr, att,
                                                     off, pos, rec, asum_mid);
  k_me<<<dim3(1), dim3(128), 0, stream>>>(asum_mid, W_edge, me);
  k_aggregate<<<dim3(N_NODES/8), dim3(256), 0, stream>>>(off, rec, xl, xr, me, att,
                                                         conv_bias, batch_vec, gsum, gcnt);
  k_rvq<<<dim3(G_GRAPHS), dim3(256), 0, stream>>>(gsum, gcnt, aW, ab, ng, nb, cbsqd,
                                                  codebooks,
                                                  outf + (size_t)G_GRAPHS*Q_QUANT*FD_OUT,
                                                  idx_i, accs);
  k_tokens<<<dim3(G_GRAPHS*Q_QUANT), dim3(256), 0, stream>>>(codebooks, idx_i, out_W, out_b,
                                                             og, ob, accs, outf,
                                                             outf + (size_t)G_GRAPHS*Q_QUANT*FD_OUT
                                                                  + (size_t)G_GRAPHS*Q_QUANT);
}